// Round 1
// baseline (724.187 us; speedup 1.0000x reference)
//
#include <hip/hip_runtime.h>

// Problem constants
#define BQ   2
#define SQ   2048
#define DIMQ 1024
#define HQ   16
#define HDQ  64
#define KQ   64
#define QKV_STRIDE (3 * DIMQ)   // 3072 floats between consecutive positions in qkv buffer

__device__ __forceinline__ float wave_max(float v) {
    for (int off = 32; off > 0; off >>= 1) v = fmaxf(v, __shfl_xor(v, off, 64));
    return v;
}
__device__ __forceinline__ float wave_sum(float v) {
    for (int off = 32; off > 0; off >>= 1) v += __shfl_xor(v, off, 64);
    return v;
}

// C[M,N] = A[M,Kd] @ Bw[N,Kd]^T + bias[N]
// 128x128 block tile, BK=16, 256 threads, 8x8 micro-tile per thread.
template <int BM, int BN, int BK>
__global__ __launch_bounds__(256) void gemm_nt(const float* __restrict__ A,
                                               const float* __restrict__ Bw,
                                               const float* __restrict__ bias,
                                               float* __restrict__ C,
                                               int M, int N, int Kd) {
    __shared__ float As[BK][BM + 4];
    __shared__ float Bs[BK][BN + 4];

    const int tid = threadIdx.x;           // 0..255
    const int tx = tid & 15;               // col group
    const int ty = tid >> 4;               // row group
    const int m0 = blockIdx.y * BM;
    const int n0 = blockIdx.x * BN;

    float acc[8][8];
#pragma unroll
    for (int i = 0; i < 8; ++i)
#pragma unroll
        for (int j = 0; j < 8; ++j) acc[i][j] = 0.f;

    const int lr = tid >> 2;               // 0..63 : row within tile (2 passes)
    const int lc = (tid & 3) * 4;          // 0,4,8,12 : col group (float4)

    for (int k0 = 0; k0 < Kd; k0 += BK) {
        // Stage A tile [BM x BK] transposed into As[BK][BM]
#pragma unroll
        for (int rr = lr; rr < BM; rr += 64) {
            const float4 a = *(const float4*)&A[(size_t)(m0 + rr) * Kd + k0 + lc];
            As[lc + 0][rr] = a.x; As[lc + 1][rr] = a.y;
            As[lc + 2][rr] = a.z; As[lc + 3][rr] = a.w;
        }
#pragma unroll
        for (int rr = lr; rr < BN; rr += 64) {
            const float4 b = *(const float4*)&Bw[(size_t)(n0 + rr) * Kd + k0 + lc];
            Bs[lc + 0][rr] = b.x; Bs[lc + 1][rr] = b.y;
            Bs[lc + 2][rr] = b.z; Bs[lc + 3][rr] = b.w;
        }
        __syncthreads();

#pragma unroll
        for (int kk = 0; kk < BK; ++kk) {
            float af[8], bf[8];
            *(float4*)&af[0] = *(const float4*)&As[kk][ty * 8];
            *(float4*)&af[4] = *(const float4*)&As[kk][ty * 8 + 4];
            *(float4*)&bf[0] = *(const float4*)&Bs[kk][tx * 8];
            *(float4*)&bf[4] = *(const float4*)&Bs[kk][tx * 8 + 4];
#pragma unroll
            for (int i = 0; i < 8; ++i)
#pragma unroll
                for (int j = 0; j < 8; ++j) acc[i][j] += af[i] * bf[j];
        }
        __syncthreads();
    }

    // Epilogue: add bias, store
    float bvals[8];
#pragma unroll
    for (int j = 0; j < 8; ++j) bvals[j] = bias[n0 + tx * 8 + j];
#pragma unroll
    for (int i = 0; i < 8; ++i) {
        const size_t row = (size_t)(m0 + ty * 8 + i);
        float4 c0, c1;
        c0.x = acc[i][0] + bvals[0]; c0.y = acc[i][1] + bvals[1];
        c0.z = acc[i][2] + bvals[2]; c0.w = acc[i][3] + bvals[3];
        c1.x = acc[i][4] + bvals[4]; c1.y = acc[i][5] + bvals[5];
        c1.z = acc[i][6] + bvals[6]; c1.w = acc[i][7] + bvals[7];
        *(float4*)&C[row * N + n0 + tx * 8]     = c0;
        *(float4*)&C[row * N + n0 + tx * 8 + 4] = c1;
    }
}

// qkv layout: [B, S, 3, H, HD] (natural GEMM1 output).
// q row  (b,s,h): base + ((b*S+s)*3 + 0)*DIM + h*HD
// k row  (b,r,h): base + ((b*S+r)*3 + 1)*DIM + h*HD
// v row  (b,r,h): base + ((b*S+r)*3 + 2)*DIM + h*HD
// out: [B, S, H*HD]  (ready for out-projection GEMM)
__global__ __launch_bounds__(256) void attn_kernel(const float* __restrict__ qkv,
                                                   const int* __restrict__ routes,
                                                   float* __restrict__ out) {
    __shared__ float q_s[4][64];
    __shared__ float w_s[4][64];
    __shared__ int   r_s[4][64];

    const int wave = threadIdx.x >> 6;
    const int lane = threadIdx.x & 63;
    const long gidx = (long)blockIdx.x * 4 + wave;   // (b*H + h)*S + q
    const int q  = (int)(gidx % SQ);
    const int bh = (int)(gidx / SQ);
    const int h  = bh % HQ;
    const int b  = bh / HQ;

    const size_t pos_base = ((size_t)(b * SQ + q) * 3) * DIMQ;
    // my route (lane j handles neighbor j)
    const int rj = routes[q * KQ + lane];

    q_s[wave][lane] = qkv[pos_base + h * HDQ + lane];   // t=0 (Q)
    r_s[wave][lane] = rj;
    __syncthreads();

    // Phase 1: scores. Lane j streams K row rj.
    const float* krow = qkv + ((size_t)(b * SQ + rj) * 3 + 1) * DIMQ + h * HDQ;
    float s = 0.f;
#pragma unroll
    for (int d4 = 0; d4 < HDQ / 4; ++d4) {
        const float4 kv = *(const float4*)&krow[d4 * 4];
        const float4 qv = *(const float4*)&q_s[wave][d4 * 4];
        s += kv.x * qv.x + kv.y * qv.y + kv.z * qv.z + kv.w * qv.w;
    }
    s *= 0.125f;  // 1/sqrt(64)

    // Softmax across the wave (64 scores)
    const float m = wave_max(s);
    const float p = __expf(s - m);
    const float l = wave_sum(p);
    w_s[wave][lane] = p / l;
    __syncthreads();

    // Phase 2: out[d] = sum_j w_j * V[r_j][d]. Lane = d; coalesced V reads.
    const float* vbase = qkv + ((size_t)b * SQ * 3 + 2) * DIMQ + h * HDQ + lane;
    float o = 0.f;
#pragma unroll 8
    for (int j = 0; j < KQ; ++j) {
        const int   r = r_s[wave][j];
        const float w = w_s[wave][j];
        o += w * vbase[(size_t)r * QKV_STRIDE];
    }
    out[((size_t)(b * SQ + q)) * DIMQ + h * HDQ + lane] = o;
}

extern "C" void kernel_launch(void* const* d_in, const int* in_sizes, int n_in,
                              void* d_out, int out_size, void* d_ws, size_t ws_size,
                              hipStream_t stream) {
    const float* x      = (const float*)d_in[0];   // [B,S,DIM]
    const float* w_qkv  = (const float*)d_in[1];   // [3*DIM, DIM]
    const float* b_qkv  = (const float*)d_in[2];   // [3*DIM]
    const float* w_out  = (const float*)d_in[3];   // [DIM, DIM]
    const float* b_out  = (const float*)d_in[4];   // [DIM]
    const int*   routes = (const int*)d_in[5];     // [S, K]
    float* out = (float*)d_out;                    // [B,S,DIM]

    float* qkv      = (float*)d_ws;                          // 4096*3072 fp32 = 48 MB
    float* attn_out = qkv + (size_t)BQ * SQ * 3 * DIMQ;      // 4096*1024 fp32 = 16 MB

    const int M = BQ * SQ;        // 4096
    dim3 blk(256);

    // 1) QKV projection: [4096,1024] @ [1024,3072]^T + b_qkv
    gemm_nt<128, 128, 16><<<dim3((3 * DIMQ) / 128, M / 128), blk, 0, stream>>>(
        x, w_qkv, b_qkv, qkv, M, 3 * DIMQ, DIMQ);

    // 2) Routed attention
    attn_kernel<<<(BQ * HQ * SQ) / 4, blk, 0, stream>>>(qkv, routes, attn_out);

    // 3) Output projection: [4096,1024] @ [1024,1024]^T + b_out
    gemm_nt<128, 128, 16><<<dim3(DIMQ / 128, M / 128), blk, 0, stream>>>(
        attn_out, w_out, b_out, out, M, DIMQ, DIMQ);
}

// Round 2
// 332.471 us; speedup vs baseline: 2.1782x; 2.1782x over previous
//
#include <hip/hip_runtime.h>

// Problem constants
#define BQ   2
#define SQ   2048
#define DIMQ 1024
#define HQ   16
#define HDQ  64
#define KQ   64
#define QKV_STRIDE (3 * DIMQ)

typedef __attribute__((ext_vector_type(8))) short short8;   // 8 bf16 (4 VGPRs)
typedef __attribute__((ext_vector_type(4))) float floatx4;  // 4 fp32 acc

typedef const __attribute__((address_space(1))) unsigned short* gas_t;
typedef __attribute__((address_space(3))) unsigned short* las_t;

__device__ __forceinline__ unsigned short f2b(float f) {
    union { float f; unsigned int u; } x; x.f = f;
    unsigned int r = x.u + 0x7fffu + ((x.u >> 16) & 1u);   // RNE
    return (unsigned short)(r >> 16);
}

__device__ __forceinline__ float wave_max(float v) {
    for (int off = 32; off > 0; off >>= 1) v = fmaxf(v, __shfl_xor(v, off, 64));
    return v;
}
__device__ __forceinline__ float wave_sum(float v) {
    for (int off = 32; off > 0; off >>= 1) v += __shfl_xor(v, off, 64);
    return v;
}

// ---------------------------------------------------------------------------
// fp32 -> bf16 cast, 4 elements / thread
__global__ __launch_bounds__(256) void cast_f32_bf16(const float* __restrict__ in,
                                                     unsigned short* __restrict__ out,
                                                     int n4) {
    int i = blockIdx.x * blockDim.x + threadIdx.x;
    if (i >= n4) return;
    float4 v = ((const float4*)in)[i];
    ushort4 o;
    o.x = f2b(v.x); o.y = f2b(v.y); o.z = f2b(v.z); o.w = f2b(v.w);
    ((ushort4*)out)[i] = o;
}

// ---------------------------------------------------------------------------
// C[M,N] = A[M,K] @ B[N,K]^T + bias[N]   (A,B bf16 row-major, C fp32)
// 128x128 tile, BK=32, 256 threads = 4 waves (2x2 of 64x64), 16x16x32 MFMA.
__global__ __launch_bounds__(256) void gemm_bf16_nt(const unsigned short* __restrict__ A,
                                                    const unsigned short* __restrict__ B,
                                                    const float* __restrict__ bias,
                                                    float* __restrict__ C,
                                                    int M, int N, int K) {
    __shared__ unsigned short As[128 * 32];   // [row][k] 8 KB
    __shared__ unsigned short Bs[128 * 32];   // [n][k]   8 KB

    const int tid  = threadIdx.x;
    const int lane = tid & 63;
    const int wv   = tid >> 6;          // 0..3
    const int wm   = (wv >> 1) * 64;    // wave row offset in tile
    const int wn   = (wv & 1) * 64;     // wave col offset in tile
    const int fr   = lane & 15;         // fragment row (m or n)
    const int fq   = lane >> 4;         // quad -> k segment (8 elems)

    const int m0 = blockIdx.y * 128;
    const int n0 = blockIdx.x * 128;

    floatx4 acc[4][4];
#pragma unroll
    for (int i = 0; i < 4; ++i)
#pragma unroll
        for (int j = 0; j < 4; ++j) acc[i][j] = (floatx4)(0.f);

    const unsigned short* Ab = A + (size_t)m0 * K;
    const unsigned short* Bb = B + (size_t)n0 * K;

    for (int k0 = 0; k0 < K; k0 += 32) {
        // Stage 8 KB A-tile + 8 KB B-tile via global_load_lds (16 B / lane).
        // chunk c (16 B): row = c>>2, kcol = (c&3)*8 ; LDS dest = base + lane*16
#pragma unroll
        for (int iss = 0; iss < 2; ++iss) {
            const int c   = iss * 256 + wv * 64 + lane;
            const int row = c >> 2;
            const int kc  = (c & 3) << 3;
            const int ldsbase = (iss * 256 + wv * 64) * 8;  // ushort index
            __builtin_amdgcn_global_load_lds(
                (gas_t)(Ab + (size_t)row * K + k0 + kc), (las_t)&As[ldsbase], 16, 0, 0);
            __builtin_amdgcn_global_load_lds(
                (gas_t)(Bb + (size_t)row * K + k0 + kc), (las_t)&Bs[ldsbase], 16, 0, 0);
        }
        __syncthreads();

        short8 af[4], bf[4];
#pragma unroll
        for (int i = 0; i < 4; ++i)
            af[i] = *(const short8*)&As[(wm + i * 16 + fr) * 32 + fq * 8];
#pragma unroll
        for (int j = 0; j < 4; ++j)
            bf[j] = *(const short8*)&Bs[(wn + j * 16 + fr) * 32 + fq * 8];
#pragma unroll
        for (int i = 0; i < 4; ++i)
#pragma unroll
            for (int j = 0; j < 4; ++j)
                acc[i][j] = __builtin_amdgcn_mfma_f32_16x16x32_bf16(af[i], bf[j], acc[i][j], 0, 0, 0);
        __syncthreads();
    }

    // Epilogue. D mapping: col = lane&15 (=fr), row = (lane>>4)*4 + reg (=fq*4+r)
    float bv[4];
#pragma unroll
    for (int j = 0; j < 4; ++j) bv[j] = bias[n0 + wn + j * 16 + fr];
#pragma unroll
    for (int i = 0; i < 4; ++i) {
#pragma unroll
        for (int r = 0; r < 4; ++r) {
            const size_t row = (size_t)(m0 + wm + i * 16 + fq * 4 + r);
#pragma unroll
            for (int j = 0; j < 4; ++j) {
                C[row * N + n0 + wn + j * 16 + fr] = acc[i][j][r] + bv[j];
            }
        }
    }
}

// ---------------------------------------------------------------------------
// qkv layout: [B, S, 3, H, HD] fp32. out: bf16 [B, S, H*HD].
__global__ __launch_bounds__(256) void attn_kernel(const float* __restrict__ qkv,
                                                   const int* __restrict__ routes,
                                                   unsigned short* __restrict__ out) {
    __shared__ float q_s[4][64];
    __shared__ float w_s[4][64];
    __shared__ int   r_s[4][64];

    const int wave = threadIdx.x >> 6;
    const int lane = threadIdx.x & 63;
    const long gidx = (long)blockIdx.x * 4 + wave;   // (b*H + h)*S + q
    const int q  = (int)(gidx % SQ);
    const int bh = (int)(gidx / SQ);
    const int h  = bh % HQ;
    const int b  = bh / HQ;

    const size_t pos_base = ((size_t)(b * SQ + q) * 3) * DIMQ;
    const int rj = routes[q * KQ + lane];

    q_s[wave][lane] = qkv[pos_base + h * HDQ + lane];
    r_s[wave][lane] = rj;
    __syncthreads();

    // Phase 1: scores. Lane j streams K row rj.
    const float* krow = qkv + ((size_t)(b * SQ + rj) * 3 + 1) * DIMQ + h * HDQ;
    float s = 0.f;
#pragma unroll
    for (int d4 = 0; d4 < HDQ / 4; ++d4) {
        const float4 kv = *(const float4*)&krow[d4 * 4];
        const float4 qv = *(const float4*)&q_s[wave][d4 * 4];
        s += kv.x * qv.x + kv.y * qv.y + kv.z * qv.z + kv.w * qv.w;
    }
    s *= 0.125f;

    const float m = wave_max(s);
    const float p = __expf(s - m);
    const float l = wave_sum(p);
    w_s[wave][lane] = p / l;
    __syncthreads();

    // Phase 2: out[d] = sum_j w_j * V[r_j][d]. Lane = d; coalesced V reads.
    const float* vbase = qkv + ((size_t)b * SQ * 3 + 2) * DIMQ + h * HDQ + lane;
    float o = 0.f;
#pragma unroll 8
    for (int j = 0; j < KQ; ++j) {
        const int   r = r_s[wave][j];
        const float w = w_s[wave][j];
        o += w * vbase[(size_t)r * QKV_STRIDE];
    }
    out[((size_t)(b * SQ + q)) * DIMQ + h * HDQ + lane] = f2b(o);
}

// ---------------------------------------------------------------------------
extern "C" void kernel_launch(void* const* d_in, const int* in_sizes, int n_in,
                              void* d_out, int out_size, void* d_ws, size_t ws_size,
                              hipStream_t stream) {
    const float* x      = (const float*)d_in[0];
    const float* w_qkv  = (const float*)d_in[1];
    const float* b_qkv  = (const float*)d_in[2];
    const float* w_out  = (const float*)d_in[3];
    const float* b_out  = (const float*)d_in[4];
    const int*   routes = (const int*)d_in[5];
    float* out = (float*)d_out;

    // ws layout (bytes): [0,48M) qkv fp32 | [48M,56M) x_bf16 / attn_bf16 (aliased)
    //                    [56M,62M) w_qkv_bf16 | [62M,64M) w_out_bf16
    char* ws = (char*)d_ws;
    float*          qkv   = (float*)ws;                                   // 12.6M fp32
    unsigned short* xb    = (unsigned short*)(ws + 50331648);             // 4.2M bf16
    unsigned short* attnb = xb;                                           // aliased
    unsigned short* wqb   = (unsigned short*)(ws + 58720256);             // 3.1M bf16
    unsigned short* wob   = (unsigned short*)(ws + 65011712);             // 1.0M bf16

    const int M = BQ * SQ;   // 4096
    dim3 blk(256);

    // Casts
    cast_f32_bf16<<<(M * DIMQ / 4 + 255) / 256, blk, 0, stream>>>(x, xb, M * DIMQ / 4);
    cast_f32_bf16<<<(3 * DIMQ * DIMQ / 4 + 255) / 256, blk, 0, stream>>>(w_qkv, wqb, 3 * DIMQ * DIMQ / 4);
    cast_f32_bf16<<<(DIMQ * DIMQ / 4 + 255) / 256, blk, 0, stream>>>(w_out, wob, DIMQ * DIMQ / 4);

    // 1) QKV projection: [4096,1024] @ [1024,3072]^T + b_qkv -> qkv fp32
    gemm_bf16_nt<<<dim3(3 * DIMQ / 128, M / 128), blk, 0, stream>>>(
        xb, wqb, b_qkv, qkv, M, 3 * DIMQ, DIMQ);

    // 2) Routed attention (fp32 compute, bf16 output)
    attn_kernel<<<(BQ * HQ * SQ) / 4, blk, 0, stream>>>(qkv, routes, attnb);

    // 3) Output projection: [4096,1024] @ [1024,1024]^T + b_out -> out fp32
    gemm_bf16_nt<<<dim3(DIMQ / 128, M / 128), blk, 0, stream>>>(
        attnb, wob, b_out, out, M, DIMQ, DIMQ);
}

// Round 3
// 251.497 us; speedup vs baseline: 2.8795x; 1.3220x over previous
//
#include <hip/hip_runtime.h>

// Problem constants
#define BQ   2
#define SQ   2048
#define DIMQ 1024
#define HQ   16
#define HDQ  64
#define KQ   64
#define QKV_STRIDE (3 * DIMQ)

typedef __attribute__((ext_vector_type(8))) short short8;   // 8 bf16 (4 VGPRs)
typedef __attribute__((ext_vector_type(4))) float floatx4;  // 4 fp32 acc

typedef const __attribute__((address_space(1))) unsigned short* gas_t;
typedef __attribute__((address_space(3))) unsigned short* las_t;

__device__ __forceinline__ unsigned short f2b(float f) {
    union { float f; unsigned int u; } x; x.f = f;
    unsigned int r = x.u + 0x7fffu + ((x.u >> 16) & 1u);   // RNE
    return (unsigned short)(r >> 16);
}

// ---------------------------------------------------------------------------
// fp32 -> bf16 cast, 4 elements / thread
__global__ __launch_bounds__(256) void cast_f32_bf16(const float* __restrict__ in,
                                                     unsigned short* __restrict__ out,
                                                     int n4) {
    int i = blockIdx.x * blockDim.x + threadIdx.x;
    if (i >= n4) return;
    float4 v = ((const float4*)in)[i];
    ushort4 o;
    o.x = f2b(v.x); o.y = f2b(v.y); o.z = f2b(v.z); o.w = f2b(v.w);
    ((ushort4*)out)[i] = o;
}

// ---------------------------------------------------------------------------
// C[M,N] = A[M,K] @ B[N,K]^T + bias[N]   (A,B bf16 row-major, C fp32)
// 128x128 tile, BK=32, 256 threads = 4 waves (2x2 of 64x64), 16x16x32 MFMA.
__global__ __launch_bounds__(256) void gemm_bf16_nt(const unsigned short* __restrict__ A,
                                                    const unsigned short* __restrict__ B,
                                                    const float* __restrict__ bias,
                                                    float* __restrict__ C,
                                                    int M, int N, int K) {
    __shared__ unsigned short As[128 * 32];   // [row][k] 8 KB
    __shared__ unsigned short Bs[128 * 32];   // [n][k]   8 KB

    const int tid  = threadIdx.x;
    const int lane = tid & 63;
    const int wv   = tid >> 6;          // 0..3
    const int wm   = (wv >> 1) * 64;    // wave row offset in tile
    const int wn   = (wv & 1) * 64;     // wave col offset in tile
    const int fr   = lane & 15;         // fragment row (m or n)
    const int fq   = lane >> 4;         // quad -> k segment (8 elems)

    const int m0 = blockIdx.y * 128;
    const int n0 = blockIdx.x * 128;

    floatx4 acc[4][4];
#pragma unroll
    for (int i = 0; i < 4; ++i)
#pragma unroll
        for (int j = 0; j < 4; ++j) acc[i][j] = (floatx4)(0.f);

    const unsigned short* Ab = A + (size_t)m0 * K;
    const unsigned short* Bb = B + (size_t)n0 * K;

    for (int k0 = 0; k0 < K; k0 += 32) {
#pragma unroll
        for (int iss = 0; iss < 2; ++iss) {
            const int c   = iss * 256 + wv * 64 + lane;
            const int row = c >> 2;
            const int kc  = (c & 3) << 3;
            const int ldsbase = (iss * 256 + wv * 64) * 8;  // ushort index
            __builtin_amdgcn_global_load_lds(
                (gas_t)(Ab + (size_t)row * K + k0 + kc), (las_t)&As[ldsbase], 16, 0, 0);
            __builtin_amdgcn_global_load_lds(
                (gas_t)(Bb + (size_t)row * K + k0 + kc), (las_t)&Bs[ldsbase], 16, 0, 0);
        }
        __syncthreads();

        short8 af[4], bf[4];
#pragma unroll
        for (int i = 0; i < 4; ++i)
            af[i] = *(const short8*)&As[(wm + i * 16 + fr) * 32 + fq * 8];
#pragma unroll
        for (int j = 0; j < 4; ++j)
            bf[j] = *(const short8*)&Bs[(wn + j * 16 + fr) * 32 + fq * 8];
#pragma unroll
        for (int i = 0; i < 4; ++i)
#pragma unroll
            for (int j = 0; j < 4; ++j)
                acc[i][j] = __builtin_amdgcn_mfma_f32_16x16x32_bf16(af[i], bf[j], acc[i][j], 0, 0, 0);
        __syncthreads();
    }

    // Epilogue. D mapping: col = lane&15 (=fr), row = (lane>>4)*4 + reg (=fq*4+r)
    float bv[4];
#pragma unroll
    for (int j = 0; j < 4; ++j) bv[j] = bias[n0 + wn + j * 16 + fr];
#pragma unroll
    for (int i = 0; i < 4; ++i) {
#pragma unroll
        for (int r = 0; r < 4; ++r) {
            const size_t row = (size_t)(m0 + wm + i * 16 + fq * 4 + r);
#pragma unroll
            for (int j = 0; j < 4; ++j) {
                C[row * N + n0 + wn + j * 16 + fr] = acc[i][j][r] + bv[j];
            }
        }
    }
}

// ---------------------------------------------------------------------------
// One block per (b,q); 256 threads; thread t = (head h = t>>4, dims 4*(t&15)).
// All K/V gathers are fully coalesced 4 KB row reads (16 heads contiguous).
// qkv: [B, S, 3, H, HD] fp32. out: bf16 [B, S, H*HD].
__global__ __launch_bounds__(256) void attn_kernel(const float* __restrict__ qkv,
                                                   const int* __restrict__ routes,
                                                   unsigned short* __restrict__ out) {
    __shared__ float s_s[HQ][KQ + 1];   // scores -> probs, padded
    __shared__ int   r_s[KQ];

    const int t  = threadIdx.x;          // 0..255
    const int id = blockIdx.x;
    // XCD-contiguity swizzle: same XCD (id%8) gets a contiguous bq range.
    const int bq = (id & 7) * 512 + (id >> 3);
    const int b  = bq >> 11;
    const int q  = bq & 2047;

    if (t < KQ) r_s[t] = routes[q * KQ + t];

    // Thread t's Q fragment: dims t*4..t*4+3 of the 1024-wide position row.
    const float4 q4 = *(const float4*)&qkv[((size_t)bq * 3) * DIMQ + t * 4];

    __syncthreads();

    const int h = t >> 4;
    const size_t baseK = ((size_t)b * SQ * 3 + 1) * DIMQ + t * 4;
    const size_t baseV = ((size_t)b * SQ * 3 + 2) * DIMQ + t * 4;

    // Phase 1: scores. Coalesced 4 KB K-row read per j; 16-lane head reduce.
#pragma unroll 8
    for (int j = 0; j < KQ; ++j) {
        const int r = r_s[j];
        const float4 k4 = *(const float4*)&qkv[baseK + (size_t)r * QKV_STRIDE];
        float p = q4.x * k4.x + q4.y * k4.y + q4.z * k4.z + q4.w * k4.w;
        p += __shfl_xor(p, 1, 64);
        p += __shfl_xor(p, 2, 64);
        p += __shfl_xor(p, 4, 64);
        p += __shfl_xor(p, 8, 64);
        if ((t & 15) == 0) s_s[h][j] = p * 0.125f;
    }
    __syncthreads();

    // Softmax: wave w handles heads 4w..4w+3; 16 lanes per head, 4 scores each.
    {
        const int lane = t & 63;
        const int sh   = ((t >> 6) << 2) + (lane >> 4);
        const int i    = lane & 15;
        float v0 = s_s[sh][i], v1 = s_s[sh][i + 16], v2 = s_s[sh][i + 32], v3 = s_s[sh][i + 48];
        float mx = fmaxf(fmaxf(v0, v1), fmaxf(v2, v3));
        mx = fmaxf(mx, __shfl_xor(mx, 1, 64));
        mx = fmaxf(mx, __shfl_xor(mx, 2, 64));
        mx = fmaxf(mx, __shfl_xor(mx, 4, 64));
        mx = fmaxf(mx, __shfl_xor(mx, 8, 64));
        float e0 = __expf(v0 - mx), e1 = __expf(v1 - mx);
        float e2 = __expf(v2 - mx), e3 = __expf(v3 - mx);
        float sm = e0 + e1 + e2 + e3;
        sm += __shfl_xor(sm, 1, 64);
        sm += __shfl_xor(sm, 2, 64);
        sm += __shfl_xor(sm, 4, 64);
        sm += __shfl_xor(sm, 8, 64);
        const float inv = 1.0f / sm;
        s_s[sh][i]      = e0 * inv;
        s_s[sh][i + 16] = e1 * inv;
        s_s[sh][i + 32] = e2 * inv;
        s_s[sh][i + 48] = e3 * inv;
    }
    __syncthreads();

    // Phase 2: coalesced 4 KB V-row read per j; prob broadcast from LDS.
    float4 o = make_float4(0.f, 0.f, 0.f, 0.f);
#pragma unroll 8
    for (int j = 0; j < KQ; ++j) {
        const int   r = r_s[j];
        const float w = s_s[h][j];
        const float4 v4 = *(const float4*)&qkv[baseV + (size_t)r * QKV_STRIDE];
        o.x += w * v4.x; o.y += w * v4.y; o.z += w * v4.z; o.w += w * v4.w;
    }
    ushort4 ob;
    ob.x = f2b(o.x); ob.y = f2b(o.y); ob.z = f2b(o.z); ob.w = f2b(o.w);
    *(ushort4*)&out[(size_t)bq * DIMQ + t * 4] = ob;
}

// ---------------------------------------------------------------------------
extern "C" void kernel_launch(void* const* d_in, const int* in_sizes, int n_in,
                              void* d_out, int out_size, void* d_ws, size_t ws_size,
                              hipStream_t stream) {
    const float* x      = (const float*)d_in[0];
    const float* w_qkv  = (const float*)d_in[1];
    const float* b_qkv  = (const float*)d_in[2];
    const float* w_out  = (const float*)d_in[3];
    const float* b_out  = (const float*)d_in[4];
    const int*   routes = (const int*)d_in[5];
    float* out = (float*)d_out;

    // ws layout (bytes): [0,48M) qkv fp32 | [48M,56M) x_bf16 / attn_bf16 (aliased)
    //                    [56M,62M) w_qkv_bf16 | [62M,64M) w_out_bf16
    char* ws = (char*)d_ws;
    float*          qkv   = (float*)ws;
    unsigned short* xb    = (unsigned short*)(ws + 50331648);
    unsigned short* attnb = xb;                                  // aliased
    unsigned short* wqb   = (unsigned short*)(ws + 58720256);
    unsigned short* wob   = (unsigned short*)(ws + 65011712);

    const int M = BQ * SQ;   // 4096
    dim3 blk(256);

    // Casts
    cast_f32_bf16<<<(M * DIMQ / 4 + 255) / 256, blk, 0, stream>>>(x, xb, M * DIMQ / 4);
    cast_f32_bf16<<<(3 * DIMQ * DIMQ / 4 + 255) / 256, blk, 0, stream>>>(w_qkv, wqb, 3 * DIMQ * DIMQ / 4);
    cast_f32_bf16<<<(DIMQ * DIMQ / 4 + 255) / 256, blk, 0, stream>>>(w_out, wob, DIMQ * DIMQ / 4);

    // 1) QKV projection: [4096,1024] @ [1024,3072]^T + b_qkv -> qkv fp32
    gemm_bf16_nt<<<dim3(3 * DIMQ / 128, M / 128), blk, 0, stream>>>(
        xb, wqb, b_qkv, qkv, M, 3 * DIMQ, DIMQ);

    // 2) Routed attention: one block per (b,q)
    attn_kernel<<<BQ * SQ, blk, 0, stream>>>(qkv, routes, attnb);

    // 3) Output projection: [4096,1024] @ [1024,1024]^T + b_out -> out fp32
    gemm_bf16_nt<<<dim3(DIMQ / 128, M / 128), blk, 0, stream>>>(
        attnb, wob, b_out, out, M, DIMQ, DIMQ);
}

// Round 4
// 207.453 us; speedup vs baseline: 3.4909x; 1.2123x over previous
//
#include <hip/hip_runtime.h>

// Problem constants
#define BQ   2
#define SQ   2048
#define DIMQ 1024
#define HQ   16
#define HDQ  64
#define KQ   64
#define QKV_STRIDE (3 * DIMQ)

typedef __attribute__((ext_vector_type(8))) short short8;   // 8 bf16 (4 VGPRs)
typedef __attribute__((ext_vector_type(4))) float floatx4;  // 4 fp32 acc

typedef const __attribute__((address_space(1))) unsigned short* gas_t;
typedef __attribute__((address_space(3))) unsigned short* las_t;

__device__ __forceinline__ unsigned short f2b(float f) {
    union { float f; unsigned int u; } x; x.f = f;
    unsigned int r = x.u + 0x7fffu + ((x.u >> 16) & 1u);   // RNE
    return (unsigned short)(r >> 16);
}
__device__ __forceinline__ float b2f(unsigned short u) {
    union { unsigned int u; float f; } x; x.u = ((unsigned int)u) << 16;
    return x.f;
}

// ---------------------------------------------------------------------------
// fp32 -> bf16 cast, 4 elements / thread
__global__ __launch_bounds__(256) void cast_f32_bf16(const float* __restrict__ in,
                                                     unsigned short* __restrict__ out,
                                                     int n4) {
    int i = blockIdx.x * blockDim.x + threadIdx.x;
    if (i >= n4) return;
    float4 v = ((const float4*)in)[i];
    ushort4 o;
    o.x = f2b(v.x); o.y = f2b(v.y); o.z = f2b(v.z); o.w = f2b(v.w);
    ((ushort4*)out)[i] = o;
}

// ---------------------------------------------------------------------------
// C[M,N] = A[M,K] @ B[N,K]^T + bias[N]   (A,B bf16 row-major; C fp32 or bf16)
// 128x128 tile, BK=32, 256 threads = 4 waves (2x2 of 64x64), 16x16x32 MFMA.
template <typename CT>
__global__ __launch_bounds__(256) void gemm_bf16_nt(const unsigned short* __restrict__ A,
                                                    const unsigned short* __restrict__ B,
                                                    const float* __restrict__ bias,
                                                    CT* __restrict__ C,
                                                    int M, int N, int K) {
    __shared__ unsigned short As[128 * 32];   // [row][k] 8 KB
    __shared__ unsigned short Bs[128 * 32];   // [n][k]   8 KB

    const int tid  = threadIdx.x;
    const int lane = tid & 63;
    const int wv   = tid >> 6;          // 0..3
    const int wm   = (wv >> 1) * 64;    // wave row offset in tile
    const int wn   = (wv & 1) * 64;     // wave col offset in tile
    const int fr   = lane & 15;         // fragment row (m or n)
    const int fq   = lane >> 4;         // quad -> k segment (8 elems)

    const int m0 = blockIdx.y * 128;
    const int n0 = blockIdx.x * 128;

    floatx4 acc[4][4];
#pragma unroll
    for (int i = 0; i < 4; ++i)
#pragma unroll
        for (int j = 0; j < 4; ++j) acc[i][j] = (floatx4)(0.f);

    const unsigned short* Ab = A + (size_t)m0 * K;
    const unsigned short* Bb = B + (size_t)n0 * K;

    for (int k0 = 0; k0 < K; k0 += 32) {
#pragma unroll
        for (int iss = 0; iss < 2; ++iss) {
            const int c   = iss * 256 + wv * 64 + lane;
            const int row = c >> 2;
            const int kc  = (c & 3) << 3;
            const int ldsbase = (iss * 256 + wv * 64) * 8;  // ushort index
            __builtin_amdgcn_global_load_lds(
                (gas_t)(Ab + (size_t)row * K + k0 + kc), (las_t)&As[ldsbase], 16, 0, 0);
            __builtin_amdgcn_global_load_lds(
                (gas_t)(Bb + (size_t)row * K + k0 + kc), (las_t)&Bs[ldsbase], 16, 0, 0);
        }
        __syncthreads();

        short8 af[4], bf[4];
#pragma unroll
        for (int i = 0; i < 4; ++i)
            af[i] = *(const short8*)&As[(wm + i * 16 + fr) * 32 + fq * 8];
#pragma unroll
        for (int j = 0; j < 4; ++j)
            bf[j] = *(const short8*)&Bs[(wn + j * 16 + fr) * 32 + fq * 8];
#pragma unroll
        for (int i = 0; i < 4; ++i)
#pragma unroll
            for (int j = 0; j < 4; ++j)
                acc[i][j] = __builtin_amdgcn_mfma_f32_16x16x32_bf16(af[i], bf[j], acc[i][j], 0, 0, 0);
        __syncthreads();
    }

    // Epilogue. D mapping: col = lane&15 (=fr), row = (lane>>4)*4 + reg (=fq*4+r)
    float bv[4];
#pragma unroll
    for (int j = 0; j < 4; ++j) bv[j] = bias[n0 + wn + j * 16 + fr];
#pragma unroll
    for (int i = 0; i < 4; ++i) {
#pragma unroll
        for (int r = 0; r < 4; ++r) {
            const size_t row = (size_t)(m0 + wm + i * 16 + fq * 4 + r);
#pragma unroll
            for (int j = 0; j < 4; ++j) {
                const float v = acc[i][j][r] + bv[j];
                if constexpr (sizeof(CT) == 2)
                    C[row * N + n0 + wn + j * 16 + fr] = (CT)f2b(v);
                else
                    C[row * N + n0 + wn + j * 16 + fr] = (CT)v;
            }
        }
    }
}

// ---------------------------------------------------------------------------
// One block per (b,q); 256 threads.
// Thread t: j-group g = t>>7, head h = (t&127)>>3, dims d0 = (t&7)*8 (8 bf16 = 16 B).
// Each iteration gathers TWO routed rows (2 KB each, fully coalesced 16 B/lane).
// qkv: bf16 [B, S, 3, H, HD]. out: bf16 [B, S, H*HD].
__global__ __launch_bounds__(256) void attn_kernel(const unsigned short* __restrict__ qkv,
                                                   const int* __restrict__ routes,
                                                   unsigned short* __restrict__ out) {
    __shared__ float s_s[HQ][KQ + 1];     // scores -> probs (4.2 KB)
    __shared__ int   r_s[KQ];
    __shared__ float o_part[8][132];      // j-group-1 partials, stride-1 conflict-free

    const int t  = threadIdx.x;           // 0..255
    const int id = blockIdx.x;
    // XCD-contiguity swizzle: same XCD (id%8) gets a contiguous bq range.
    const int bq = (id & 7) * 512 + (id >> 3);
    const int b  = bq >> 11;
    const int q  = bq & 2047;

    if (t < KQ) r_s[t] = routes[q * KQ + t];

    const int g    = t >> 7;              // j-group: 0 or 1
    const int th   = t & 127;
    const int h    = th >> 3;             // head
    const int d0   = (t & 7) * 8;         // dim offset within head

    // Q fragment: 8 bf16 -> 8 floats (same for both j-groups)
    float qf[8];
    {
        const short8 q8 = *(const short8*)&qkv[((size_t)bq * 3) * DIMQ + h * HDQ + d0];
#pragma unroll
        for (int e = 0; e < 8; ++e) qf[e] = b2f((unsigned short)q8[e]);
    }
    __syncthreads();

    const size_t baseK = ((size_t)b * SQ * 3 + 1) * DIMQ + h * HDQ + d0;
    const size_t baseV = ((size_t)b * SQ * 3 + 2) * DIMQ + h * HDQ + d0;

    // Phase 1: scores. 2 routed K-rows per iteration; 8-lane head-group reduce.
#pragma unroll 8
    for (int jj = 0; jj < KQ / 2; ++jj) {
        const int j = jj * 2 + g;
        const int r = r_s[j];
        const short8 k8 = *(const short8*)&qkv[baseK + (size_t)r * QKV_STRIDE];
        float p = 0.f;
#pragma unroll
        for (int e = 0; e < 8; ++e) p += qf[e] * b2f((unsigned short)k8[e]);
        p += __shfl_xor(p, 1, 64);
        p += __shfl_xor(p, 2, 64);
        p += __shfl_xor(p, 4, 64);
        if ((t & 7) == 0) s_s[h][j] = p * 0.125f;
    }
    __syncthreads();

    // Softmax: wave w handles heads 4w..4w+3; 16 lanes per head, 4 scores each.
    {
        const int lane = t & 63;
        const int sh   = ((t >> 6) << 2) + (lane >> 4);
        const int i    = lane & 15;
        float v0 = s_s[sh][i], v1 = s_s[sh][i + 16], v2 = s_s[sh][i + 32], v3 = s_s[sh][i + 48];
        float mx = fmaxf(fmaxf(v0, v1), fmaxf(v2, v3));
        mx = fmaxf(mx, __shfl_xor(mx, 1, 64));
        mx = fmaxf(mx, __shfl_xor(mx, 2, 64));
        mx = fmaxf(mx, __shfl_xor(mx, 4, 64));
        mx = fmaxf(mx, __shfl_xor(mx, 8, 64));
        float e0 = __expf(v0 - mx), e1 = __expf(v1 - mx);
        float e2 = __expf(v2 - mx), e3 = __expf(v3 - mx);
        float sm = e0 + e1 + e2 + e3;
        sm += __shfl_xor(sm, 1, 64);
        sm += __shfl_xor(sm, 2, 64);
        sm += __shfl_xor(sm, 4, 64);
        sm += __shfl_xor(sm, 8, 64);
        const float inv = 1.0f / sm;
        s_s[sh][i]      = e0 * inv;
        s_s[sh][i + 16] = e1 * inv;
        s_s[sh][i + 32] = e2 * inv;
        s_s[sh][i + 48] = e3 * inv;
    }
    __syncthreads();

    // Phase 2: 2 routed V-rows per iteration; each j-group sums its half.
    float o[8];
#pragma unroll
    for (int e = 0; e < 8; ++e) o[e] = 0.f;
#pragma unroll 8
    for (int jj = 0; jj < KQ / 2; ++jj) {
        const int   j = jj * 2 + g;
        const int   r = r_s[j];
        const float w = s_s[h][j];
        const short8 v8 = *(const short8*)&qkv[baseV + (size_t)r * QKV_STRIDE];
#pragma unroll
        for (int e = 0; e < 8; ++e) o[e] += w * b2f((unsigned short)v8[e]);
    }
    if (g == 1) {
#pragma unroll
        for (int e = 0; e < 8; ++e) o_part[e][th] = o[e];
    }
    __syncthreads();
    if (g == 0) {
        ushort4 lo, hi;
        lo.x = f2b(o[0] + o_part[0][th]); lo.y = f2b(o[1] + o_part[1][th]);
        lo.z = f2b(o[2] + o_part[2][th]); lo.w = f2b(o[3] + o_part[3][th]);
        hi.x = f2b(o[4] + o_part[4][th]); hi.y = f2b(o[5] + o_part[5][th]);
        hi.z = f2b(o[6] + o_part[6][th]); hi.w = f2b(o[7] + o_part[7][th]);
        ushort4* dst = (ushort4*)&out[(size_t)bq * DIMQ + h * HDQ + d0];
        dst[0] = lo; dst[1] = hi;
    }
}

// ---------------------------------------------------------------------------
extern "C" void kernel_launch(void* const* d_in, const int* in_sizes, int n_in,
                              void* d_out, int out_size, void* d_ws, size_t ws_size,
                              hipStream_t stream) {
    const float* x      = (const float*)d_in[0];
    const float* w_qkv  = (const float*)d_in[1];
    const float* b_qkv  = (const float*)d_in[2];
    const float* w_out  = (const float*)d_in[3];
    const float* b_out  = (const float*)d_in[4];
    const int*   routes = (const int*)d_in[5];
    float* out = (float*)d_out;

    // ws layout (bytes): [0,24M) qkv bf16 | [24M,32M+)=xb / attnb (aliased)
    //                    then w_qkv_bf16, w_out_bf16
    char* ws = (char*)d_ws;
    unsigned short* qkvb  = (unsigned short*)ws;                      // 12.6M bf16 = 24 MB
    unsigned short* xb    = (unsigned short*)(ws + 25165824);         // 8.4 MB
    unsigned short* attnb = xb;                                       // aliased
    unsigned short* wqb   = (unsigned short*)(ws + 33554432);         // 6.3 MB
    unsigned short* wob   = (unsigned short*)(ws + 39845888);         // 2.1 MB

    const int M = BQ * SQ;   // 4096
    dim3 blk(256);

    // Casts
    cast_f32_bf16<<<(M * DIMQ / 4 + 255) / 256, blk, 0, stream>>>(x, xb, M * DIMQ / 4);
    cast_f32_bf16<<<(3 * DIMQ * DIMQ / 4 + 255) / 256, blk, 0, stream>>>(w_qkv, wqb, 3 * DIMQ * DIMQ / 4);
    cast_f32_bf16<<<(DIMQ * DIMQ / 4 + 255) / 256, blk, 0, stream>>>(w_out, wob, DIMQ * DIMQ / 4);

    // 1) QKV projection -> bf16 qkv [B,S,3,H,HD]
    gemm_bf16_nt<unsigned short><<<dim3(3 * DIMQ / 128, M / 128), blk, 0, stream>>>(
        xb, wqb, b_qkv, qkvb, M, 3 * DIMQ, DIMQ);

    // 2) Routed attention: one block per (b,q), bf16 gathers
    attn_kernel<<<BQ * SQ, blk, 0, stream>>>(qkvb, routes, attnb);

    // 3) Output projection -> fp32 final output
    gemm_bf16_nt<float><<<dim3(DIMQ / 128, M / 128), blk, 0, stream>>>(
        attnb, wob, b_out, out, M, DIMQ, DIMQ);
}

// Round 5
// 202.278 us; speedup vs baseline: 3.5802x; 1.0256x over previous
//
#include <hip/hip_runtime.h>

// Problem constants
#define BQ   2
#define SQ   2048
#define DIMQ 1024
#define HQ   16
#define HDQ  64
#define KQ   64
#define QKV_STRIDE (3 * DIMQ)

typedef __attribute__((ext_vector_type(8))) short short8;   // 8 bf16 (4 VGPRs)
typedef __attribute__((ext_vector_type(4))) float floatx4;  // 4 fp32 acc

typedef const __attribute__((address_space(1))) unsigned short* gas_t;
typedef __attribute__((address_space(3))) unsigned short* las_t;

__device__ __forceinline__ unsigned short f2b(float f) {
    union { float f; unsigned int u; } x; x.f = f;
    unsigned int r = x.u + 0x7fffu + ((x.u >> 16) & 1u);   // RNE
    return (unsigned short)(r >> 16);
}
__device__ __forceinline__ float b2f(unsigned short u) {
    union { unsigned int u; float f; } x; x.u = ((unsigned int)u) << 16;
    return x.f;
}

// ---------------------------------------------------------------------------
// Fused fp32 -> bf16 cast over three buffers (x, w_qkv, w_out), float4 lanes.
__global__ __launch_bounds__(256) void cast3_f32_bf16(const float* __restrict__ s0, unsigned short* __restrict__ d0, int n0,
                                                      const float* __restrict__ s1, unsigned short* __restrict__ d1, int n1,
                                                      const float* __restrict__ s2, unsigned short* __restrict__ d2, int n2) {
    int i = blockIdx.x * blockDim.x + threadIdx.x;
    const float* s; unsigned short* d;
    if (i < n0)                { s = s0; d = d0; }
    else if (i < n0 + n1)      { s = s1; d = d1; i -= n0; }
    else if (i < n0 + n1 + n2) { s = s2; d = d2; i -= n0 + n1; }
    else return;
    float4 v = ((const float4*)s)[i];
    ushort4 o;
    o.x = f2b(v.x); o.y = f2b(v.y); o.z = f2b(v.z); o.w = f2b(v.w);
    ((ushort4*)d)[i] = o;
}

// ---------------------------------------------------------------------------
// C[M,N] = A[M,K] @ B[N,K]^T + bias[N]   (A,B bf16 row-major; C fp32 or bf16)
// BMxBN tile, BK=32, 256 threads = 4 waves (2x2 of BM/2 x BN/2), 16x16x32 MFMA.
template <int BM, int BN, typename CT>
__global__ __launch_bounds__(256) void gemm_bf16_nt(const unsigned short* __restrict__ A,
                                                    const unsigned short* __restrict__ B,
                                                    const float* __restrict__ bias,
                                                    CT* __restrict__ C,
                                                    int M, int N, int K) {
    constexpr int MI = BM / 32;          // mfma tiles per wave (rows)
    constexpr int NJ = BN / 32;          // mfma tiles per wave (cols)
    __shared__ unsigned short As[BM * 32];
    __shared__ unsigned short Bs[BN * 32];

    const int tid  = threadIdx.x;
    const int lane = tid & 63;
    const int wv   = tid >> 6;            // 0..3
    const int wm   = (wv >> 1) * (BM / 2);
    const int wn   = (wv & 1) * (BN / 2);
    const int fr   = lane & 15;           // fragment row (m or n)
    const int fq   = lane >> 4;           // quad -> k segment (8 elems)

    const int m0 = blockIdx.y * BM;
    const int n0 = blockIdx.x * BN;

    floatx4 acc[MI][NJ];
#pragma unroll
    for (int i = 0; i < MI; ++i)
#pragma unroll
        for (int j = 0; j < NJ; ++j) acc[i][j] = (floatx4)(0.f);

    const unsigned short* Ab = A + (size_t)m0 * K;
    const unsigned short* Bb = B + (size_t)n0 * K;

    for (int k0 = 0; k0 < K; k0 += 32) {
        // Stage A (BM*4 chunks of 16 B) then B (BN*4 chunks) via global_load_lds.
        // chunk c: row = c>>2, kcol = (c&3)*8 ; LDS ushort index = c*8.
#pragma unroll
        for (int c = 0; c < (BM + BN) * 4; c += 256) {
            const int cc = c + tid;
            if (cc < BM * 4) {
                __builtin_amdgcn_global_load_lds(
                    (gas_t)(Ab + (size_t)(cc >> 2) * K + k0 + ((cc & 3) << 3)),
                    (las_t)&As[cc * 8], 16, 0, 0);
            } else {
                const int c2 = cc - BM * 4;
                __builtin_amdgcn_global_load_lds(
                    (gas_t)(Bb + (size_t)(c2 >> 2) * K + k0 + ((c2 & 3) << 3)),
                    (las_t)&Bs[c2 * 8], 16, 0, 0);
            }
        }
        __syncthreads();

        short8 af[MI], bf[NJ];
#pragma unroll
        for (int i = 0; i < MI; ++i)
            af[i] = *(const short8*)&As[(wm + i * 16 + fr) * 32 + fq * 8];
#pragma unroll
        for (int j = 0; j < NJ; ++j)
            bf[j] = *(const short8*)&Bs[(wn + j * 16 + fr) * 32 + fq * 8];
#pragma unroll
        for (int i = 0; i < MI; ++i)
#pragma unroll
            for (int j = 0; j < NJ; ++j)
                acc[i][j] = __builtin_amdgcn_mfma_f32_16x16x32_bf16(af[i], bf[j], acc[i][j], 0, 0, 0);
        __syncthreads();
    }

    // Epilogue. D mapping: col = lane&15 (=fr), row = (lane>>4)*4 + reg (=fq*4+r)
    float bv[NJ];
#pragma unroll
    for (int j = 0; j < NJ; ++j) bv[j] = bias[n0 + wn + j * 16 + fr];
#pragma unroll
    for (int i = 0; i < MI; ++i) {
#pragma unroll
        for (int r = 0; r < 4; ++r) {
            const size_t row = (size_t)(m0 + wm + i * 16 + fq * 4 + r);
#pragma unroll
            for (int j = 0; j < NJ; ++j) {
                const float v = acc[i][j][r] + bv[j];
                if constexpr (sizeof(CT) == 2)
                    C[row * N + n0 + wn + j * 16 + fr] = (CT)f2b(v);
                else
                    C[row * N + n0 + wn + j * 16 + fr] = (CT)v;
            }
        }
    }
}

// ---------------------------------------------------------------------------
// One block per (b,q); 256 threads; online softmax, single fused gather loop.
// Thread t: j-group g = t>>7, head h = (t&127)>>3, dims d0 = (t&7)*8 (16 B).
// Each iteration gathers one K-row and one V-row (both in flight together).
// qkv: bf16 [B, S, 3, H, HD]. out: bf16 [B, S, H*HD].
__global__ __launch_bounds__(256) void attn_kernel(const unsigned short* __restrict__ qkv,
                                                   const int* __restrict__ routes,
                                                   unsigned short* __restrict__ out) {
    __shared__ int   r_s[KQ];
    __shared__ float m_s[128], l_s[128];
    __shared__ float o_part[8][128];

    const int t  = threadIdx.x;           // 0..255
    const int id = blockIdx.x;
    // XCD-contiguity swizzle: same XCD (id%8) gets a contiguous bq range.
    const int bq = (id & 7) * 512 + (id >> 3);
    const int b  = bq >> 11;
    const int q  = bq & 2047;

    if (t < KQ) r_s[t] = routes[q * KQ + t];

    const int g  = t >> 7;                // j-group: 0 or 1
    const int th = t & 127;
    const int h  = th >> 3;               // head
    const int d0 = (t & 7) * 8;           // dim offset within head

    float qf[8];
    {
        const short8 q8 = *(const short8*)&qkv[((size_t)bq * 3) * DIMQ + h * HDQ + d0];
#pragma unroll
        for (int e = 0; e < 8; ++e) qf[e] = b2f((unsigned short)q8[e]);
    }
    __syncthreads();

    const size_t baseK = ((size_t)b * SQ * 3 + 1) * DIMQ + h * HDQ + d0;
    const size_t baseV = ((size_t)b * SQ * 3 + 2) * DIMQ + h * HDQ + d0;

    float m = -1e30f, l = 0.f;
    float o[8];
#pragma unroll
    for (int e = 0; e < 8; ++e) o[e] = 0.f;

#pragma unroll 4
    for (int jj = 0; jj < KQ / 2; ++jj) {
        const int j = jj * 2 + g;
        const size_t roff = (size_t)r_s[j] * QKV_STRIDE;
        const short8 k8 = *(const short8*)&qkv[baseK + roff];
        const short8 v8 = *(const short8*)&qkv[baseV + roff];
        float p = 0.f;
#pragma unroll
        for (int e = 0; e < 8; ++e) p += qf[e] * b2f((unsigned short)k8[e]);
        p += __shfl_xor(p, 1, 64);
        p += __shfl_xor(p, 2, 64);
        p += __shfl_xor(p, 4, 64);
        const float s  = p * 0.125f;
        const float mn = fmaxf(m, s);
        const float al = __expf(m - mn);
        const float pe = __expf(s - mn);
        l = l * al + pe;
#pragma unroll
        for (int e = 0; e < 8; ++e) o[e] = o[e] * al + pe * b2f((unsigned short)v8[e]);
        m = mn;
    }

    // Merge the two j-groups (online-softmax state merge), then store.
    if (g == 1) {
        m_s[th] = m; l_s[th] = l;
#pragma unroll
        for (int e = 0; e < 8; ++e) o_part[e][th] = o[e];
    }
    __syncthreads();
    if (g == 0) {
        const float m1 = m_s[th], l1 = l_s[th];
        const float mm = fmaxf(m, m1);
        const float a0 = __expf(m - mm);
        const float a1 = __expf(m1 - mm);
        const float inv = 1.0f / (l * a0 + l1 * a1);
        float oo[8];
#pragma unroll
        for (int e = 0; e < 8; ++e) oo[e] = (o[e] * a0 + o_part[e][th] * a1) * inv;
        ushort4 lo, hi;
        lo.x = f2b(oo[0]); lo.y = f2b(oo[1]); lo.z = f2b(oo[2]); lo.w = f2b(oo[3]);
        hi.x = f2b(oo[4]); hi.y = f2b(oo[5]); hi.z = f2b(oo[6]); hi.w = f2b(oo[7]);
        ushort4* dst = (ushort4*)&out[(size_t)bq * DIMQ + h * HDQ + d0];
        dst[0] = lo; dst[1] = hi;
    }
}

// ---------------------------------------------------------------------------
extern "C" void kernel_launch(void* const* d_in, const int* in_sizes, int n_in,
                              void* d_out, int out_size, void* d_ws, size_t ws_size,
                              hipStream_t stream) {
    const float* x      = (const float*)d_in[0];
    const float* w_qkv  = (const float*)d_in[1];
    const float* b_qkv  = (const float*)d_in[2];
    const float* w_out  = (const float*)d_in[3];
    const float* b_out  = (const float*)d_in[4];
    const int*   routes = (const int*)d_in[5];
    float* out = (float*)d_out;

    // ws layout (bytes): [0,24M) qkv bf16 | [24M,..) xb / attnb (aliased)
    //                    then w_qkv_bf16, w_out_bf16
    char* ws = (char*)d_ws;
    unsigned short* qkvb  = (unsigned short*)ws;                      // 24 MB
    unsigned short* xb    = (unsigned short*)(ws + 25165824);         // 8.4 MB
    unsigned short* attnb = xb;                                       // aliased
    unsigned short* wqb   = (unsigned short*)(ws + 33554432);         // 6.3 MB
    unsigned short* wob   = (unsigned short*)(ws + 39845888);         // 2.1 MB

    const int M = BQ * SQ;   // 4096
    dim3 blk(256);

    // Fused casts (x, w_qkv, w_out), float4 per thread
    {
        const int n0 = M * DIMQ / 4, n1 = 3 * DIMQ * DIMQ / 4, n2 = DIMQ * DIMQ / 4;
        cast3_f32_bf16<<<(n0 + n1 + n2 + 255) / 256, blk, 0, stream>>>(
            x, xb, n0, w_qkv, wqb, n1, w_out, wob, n2);
    }

    // 1) QKV projection -> bf16 qkv [B,S,3,H,HD]
    gemm_bf16_nt<128, 128, unsigned short><<<dim3(3 * DIMQ / 128, M / 128), blk, 0, stream>>>(
        xb, wqb, b_qkv, qkvb, M, 3 * DIMQ, DIMQ);

    // 2) Routed attention: one block per (b,q), fused online-softmax
    attn_kernel<<<BQ * SQ, blk, 0, stream>>>(qkvb, routes, attnb);

    // 3) Output projection -> fp32 final output (128x64 tiles: 512 blocks, 2/CU)
    gemm_bf16_nt<128, 64, float><<<dim3(DIMQ / 64, M / 128), blk, 0, stream>>>(
        attnb, wob, b_out, out, M, DIMQ, DIMQ);
}